// Round 3
// baseline (320.613 us; speedup 1.0000x reference)
//
#include <hip/hip_runtime.h>
#include <hip/hip_bf16.h>

#define DD 300
#define SS 512
#define NW 16          // waves per block in main kernel

// ---------------------------------------------------------------------------
// Workspace layout (floats):
//   ws[0]        = c_k = dot(bk, wk)
//   ws[1]        = c_q = dot(bq, wq)
//   ws[16..316)  = u   = wk @ Wk
//   ws[320..620) = uq  = wq @ Wq
//   ws[640..940) = bc  = Wp @ bk + bp
//   ws[1024..91024)   = Wc = Wp @ Wk   (300x300)
//   ws[91648..141648) = eu[v] = dot(emb[v], u)   (50000)
// ---------------------------------------------------------------------------
#define WC_OFF 1024
#define EU_OFF 91648

// One block per output row i (300 blocks, 960 threads = 15 waves).
// 3 groups of 320 threads split the e-dimension of the Wc row dot.
__global__ __launch_bounds__(960) void precompute_all(
    const float* __restrict__ Wk, const float* __restrict__ bk,
    const float* __restrict__ Wq, const float* __restrict__ bq,
    const float* __restrict__ w_mlp,
    const float* __restrict__ Wp, const float* __restrict__ bp,
    float* __restrict__ ws)
{
    const int i    = blockIdx.x;
    const int tid  = threadIdx.x;
    const int g    = tid / 320;      // e-split group 0..2
    const int j    = tid - g * 320;  // output column 0..319
    const int wv   = tid >> 6;
    const int lane = tid & 63;

    __shared__ float part[3][304];
    __shared__ float r1[5], r2[5], r3[5];

    // --- Wc row i, e-range [g*100, g*100+100) ---
    if (j < DD) {
        const float* wpr = Wp + i * DD;
        const int e0 = g * 100;
        float a0 = 0.f, a1 = 0.f, a2 = 0.f, a3 = 0.f;
        for (int e = e0; e < e0 + 100; e += 4) {
            a0 += wpr[e]     * Wk[(e)     * DD + j];
            a1 += wpr[e + 1] * Wk[(e + 1) * DD + j];
            a2 += wpr[e + 2] * Wk[(e + 2) * DD + j];
            a3 += wpr[e + 3] * Wk[(e + 3) * DD + j];
        }
        part[g][j] = (a0 + a1) + (a2 + a3);
    }

    // --- u[i], uq[i], bc[i]: group 0 (waves 0..4), one elem/thread ---
    float p1 = 0.f, p2 = 0.f, p3 = 0.f;
    if (g == 0 && j < DD) {
        p1 = w_mlp[j]       * Wk[j * DD + i];
        p2 = w_mlp[DD + j]  * Wq[j * DD + i];
        p3 = Wp[i * DD + j] * bk[j];
    }
    if (wv < 5) {
        #pragma unroll
        for (int off = 32; off; off >>= 1) {
            p1 += __shfl_xor(p1, off);
            p2 += __shfl_xor(p2, off);
            p3 += __shfl_xor(p3, off);
        }
        if (lane == 0) { r1[wv] = p1; r2[wv] = p2; r3[wv] = p3; }
    }
    __syncthreads();
    if (tid < DD)
        ws[WC_OFF + i * DD + tid] = part[0][tid] + part[1][tid] + part[2][tid];
    if (tid == 0) {
        float s1 = 0.f, s2 = 0.f, s3 = 0.f;
        for (int w = 0; w < 5; ++w) { s1 += r1[w]; s2 += r2[w]; s3 += r3[w]; }
        ws[16 + i]  = s1;
        ws[320 + i] = s2;
        ws[640 + i] = s3 + bp[i];
    }

    if (i == 0) {
        __syncthreads();
        float q1 = (tid < DD) ? bk[tid] * w_mlp[tid]      : 0.f;
        float q2 = (tid < DD) ? bq[tid] * w_mlp[DD + tid] : 0.f;
        #pragma unroll
        for (int off = 32; off; off >>= 1) {
            q1 += __shfl_xor(q1, off);
            q2 += __shfl_xor(q2, off);
        }
        if (lane == 0) { r1[wv] = q1; r2[wv] = q2; }
        __syncthreads();
        if (tid == 0) {
            float s1 = 0.f, s2 = 0.f;
            for (int w = 0; w < 5; ++w) { s1 += r1[w]; s2 += r2[w]; }
            ws[0] = s1;
            ws[1] = s2;
        }
    }
}

// eu[v] = dot(emb[v], u) over the whole vocab. Wave per row, grid-stride.
__global__ __launch_bounds__(1024) void compute_eu(
    const float* __restrict__ emb, float* __restrict__ ws)
{
    const int tid  = threadIdx.x;
    const int wv   = tid >> 6;
    const int lane = tid & 63;
    __shared__ __align__(16) float u_s[DD];
    if (tid < DD) u_s[tid] = ws[16 + tid];
    __syncthreads();

    const float4* u4 = (const float4*)u_s;
    const float4  q0 = u4[lane];
    const float4  q1 = (lane < 11) ? u4[64 + lane] : float4{0, 0, 0, 0};

    const int gw     = blockIdx.x * (1024 / 64) + wv;
    const int stride = gridDim.x * (1024 / 64);
    for (int v = gw; v < 50000; v += stride) {
        const float4* er = (const float4*)(emb + (size_t)v * DD);
        const float4 e0 = er[lane];
        float a = e0.x * q0.x + e0.y * q0.y + e0.z * q0.z + e0.w * q0.w;
        if (lane < 11) {
            const float4 e1 = er[64 + lane];
            a += e1.x * q1.x + e1.y * q1.y + e1.z * q1.z + e1.w * q1.w;
        }
        #pragma unroll
        for (int off = 32; off; off >>= 1) a += __shfl_xor(a, off);
        if (lane == 0) ws[EU_OFF + v] = a;
    }
}

// ---------------------------------------------------------------------------
// Main kernel: one block per batch row, 1024 threads = 16 waves.
// ---------------------------------------------------------------------------
__global__ __launch_bounds__(1024, 8) void memnet_main(
    const int* __restrict__ text, const int* __restrict__ asp,
    const float* __restrict__ emb,
    const float* __restrict__ Wx, const float* __restrict__ bx,
    const float* __restrict__ Wd, const float* __restrict__ bd,
    const float* __restrict__ ws,
    float* __restrict__ out)
{
    const int b    = blockIdx.x;
    const int tid  = threadIdx.x;
    const int wv   = tid >> 6;
    const int lane = tid & 63;

    __shared__ __align__(16) float ks[SS];
    __shared__ __align__(16) float cw[SS];
    __shared__ __align__(16) float wgt[SS];
    __shared__ __align__(16) int   ti[SS];
    __shared__ __align__(16) float xv[DD];
    __shared__ __align__(16) float xn[DD];
    __shared__ __align__(16) float mv[DD];
    __shared__ __align__(16) float uq_s[DD];
    __shared__ __align__(16) float mpart[NW][DD];
    __shared__ float red[NW];
    __shared__ float red2[NW];

    // ---- tokens + length ----
    int t = 0;
    if (tid < SS) { t = text[(size_t)b * SS + tid]; ti[tid] = t; }
    const unsigned long long bal = __ballot(tid < SS && t != 0);
    if (lane == 0) red[wv] = (float)__popcll(bal);
    __syncthreads();

    int len = 0;
    #pragma unroll
    for (int w = 0; w < NW; ++w) len += (int)red[w];
    const float lenf = (float)len;
    const int   s0   = SS - len;            // first non-pad position

    const float c_k = ws[0];
    const float c_q = ws[1];

    // wgt + ks (4B gather from eu)
    if (tid < SS) {
        const int j = tid - s0;
        const float wg = (j >= 0) ? (1.0f - (float)j / lenf) : 1.0f;
        wgt[tid] = wg;
        ks[tid] = wg * ws[EU_OFF + t] + c_k;   // eu[0]==0 -> pad ks = c_k
    }

    // folded uq + aspect mean (n_asp counted redundantly per thread)
    if (tid < DD) {
        uq_s[tid] = ws[320 + tid];
        float na = 0.f, a = 0.f;
        #pragma unroll
        for (int k = 0; k < 8; ++k) {
            const int idx = asp[b * 8 + k];    // emb[0]==0, safe
            na += (idx != 0) ? 1.0f : 0.0f;
            a += emb[(size_t)idx * DD + tid];
        }
        xv[tid] = a / na;
    }
    __syncthreads();

    // ---- hop loop ----
    for (int hop = 0; hop < 3; ++hop) {
        // xn = Wx @ xv + bx; fold qs partial into epilogue
        {
            const float4* x4 = (const float4*)xv;
            const float4  v0 = x4[lane];
            const float4  v1 = (lane < 11) ? x4[64 + lane] : float4{0, 0, 0, 0};
            float qpart = 0.f;
            for (int i = wv; i < DD; i += NW) {
                const float4* wr = (const float4*)(Wx + i * DD);
                const float4 w0 = wr[lane];
                float a = w0.x * v0.x + w0.y * v0.y + w0.z * v0.z + w0.w * v0.w;
                if (lane < 11) {
                    const float4 w1 = wr[64 + lane];
                    a += w1.x * v1.x + w1.y * v1.y + w1.z * v1.z + w1.w * v1.w;
                }
                #pragma unroll
                for (int off = 32; off; off >>= 1) a += __shfl_xor(a, off);
                if (lane == 0) {
                    const float xni = a + bx[i];
                    xn[i] = xni;
                    qpart += uq_s[i] * xni;
                }
            }
            if (lane == 0) red[wv] = qpart;
        }
        __syncthreads();                               // A

        float qs = c_q;
        #pragma unroll
        for (int w = 0; w < NW; ++w) qs += red[w];

        // p = exp(tanh(ks+qs)); cw = p*wgt
        float p = 0.f;
        if (tid < SS) {
            p = expf(tanhf(ks[tid] + qs));
            cw[tid] = p * wgt[tid];
        }
        float sp = p;
        #pragma unroll
        for (int off = 32; off; off >>= 1) sp += __shfl_xor(sp, off);
        if (lane == 0) red2[wv] = sp;
        __syncthreads();                               // B

        float sumP = 0.f;
        #pragma unroll
        for (int w = 0; w < NW; ++w) sumP += red2[w];

        // m = sum_{s>=s0} cw[s]*emb[t[s]]  (no branch: pads are a prefix)
        {
            float4 acc  = {0, 0, 0, 0};
            float4 accb = {0, 0, 0, 0};
            const int start = s0 + ((wv - s0) & (NW - 1));
            #pragma unroll 4
            for (int s = start; s < SS; s += NW) {
                const int row = ti[s];
                const float c = cw[s];
                const float4* er = (const float4*)(emb + (size_t)row * DD);
                const float4 e0 = er[lane];
                acc.x += c * e0.x; acc.y += c * e0.y;
                acc.z += c * e0.z; acc.w += c * e0.w;
                if (lane < 11) {
                    const float4 e1 = er[64 + lane];
                    accb.x += c * e1.x; accb.y += c * e1.y;
                    accb.z += c * e1.z; accb.w += c * e1.w;
                }
            }
            ((float4*)&mpart[wv][0])[lane] = acc;
            if (lane < 11) ((float4*)&mpart[wv][0])[64 + lane] = accb;
        }
        __syncthreads();                               // C

        if (tid < DD) {
            float mm = 0.f;
            #pragma unroll
            for (int w = 0; w < NW; ++w) mm += mpart[w][tid];
            mv[tid] = mm / sumP;                       // softmax norm folded
        }
        __syncthreads();                               // D

        // xv = Wc @ mv + bc + xn
        {
            const float* Wc = ws + WC_OFF;
            const float* bc = ws + 640;
            const float4* m4 = (const float4*)mv;
            const float4  v0 = m4[lane];
            const float4  v1 = (lane < 11) ? m4[64 + lane] : float4{0, 0, 0, 0};
            for (int i = wv; i < DD; i += NW) {
                const float4* wr = (const float4*)(Wc + i * DD);
                const float4 w0 = wr[lane];
                float a = w0.x * v0.x + w0.y * v0.y + w0.z * v0.z + w0.w * v0.w;
                if (lane < 11) {
                    const float4 w1 = wr[64 + lane];
                    a += w1.x * v1.x + w1.y * v1.y + w1.z * v1.z + w1.w * v1.w;
                }
                #pragma unroll
                for (int off = 32; off; off >>= 1) a += __shfl_xor(a, off);
                if (lane == 0) xv[i] = a + bc[i] + xn[i];
            }
        }
        __syncthreads();                               // E
    }

    // ---- out[b,p] = dot(Wd[p], xv) + bd[p], P=3 ----
    if (wv < 3) {
        const float4* wr = (const float4*)(Wd + wv * DD);
        const float4* x4 = (const float4*)xv;
        const float4 w0 = wr[lane];
        const float4 v0 = x4[lane];
        float a = w0.x * v0.x + w0.y * v0.y + w0.z * v0.z + w0.w * v0.w;
        if (lane < 11) {
            const float4 w1 = wr[64 + lane];
            const float4 v1 = x4[64 + lane];
            a += w1.x * v1.x + w1.y * v1.y + w1.z * v1.z + w1.w * v1.w;
        }
        #pragma unroll
        for (int off = 32; off; off >>= 1) a += __shfl_xor(a, off);
        if (lane == 0) out[b * 3 + wv] = a + bd[wv];
    }
}

extern "C" void kernel_launch(void* const* d_in, const int* in_sizes, int n_in,
                              void* d_out, int out_size, void* d_ws, size_t ws_size,
                              hipStream_t stream)
{
    const int*   text = (const int*)d_in[0];
    const int*   asp  = (const int*)d_in[1];
    const float* emb  = (const float*)d_in[2];
    const float* Wx   = (const float*)d_in[3];
    const float* bx   = (const float*)d_in[4];
    const float* Wk   = (const float*)d_in[5];
    const float* bk   = (const float*)d_in[6];
    const float* Wq   = (const float*)d_in[7];
    const float* bq   = (const float*)d_in[8];
    const float* wm   = (const float*)d_in[9];
    const float* Wp   = (const float*)d_in[10];
    const float* bp   = (const float*)d_in[11];
    const float* Wd   = (const float*)d_in[12];
    const float* bd   = (const float*)d_in[13];
    float* out = (float*)d_out;
    float* ws  = (float*)d_ws;

    precompute_all<<<300, 960, 0, stream>>>(Wk, bk, Wq, bq, wm, Wp, bp, ws);
    compute_eu<<<512, 1024, 0, stream>>>(emb, ws);
    memnet_main<<<512, 1024, 0, stream>>>(text, asp, emb, Wx, bx, Wd, bd, ws, out);
}

// Round 4
// 320.354 us; speedup vs baseline: 1.0008x; 1.0008x over previous
//
#include <hip/hip_runtime.h>
#include <hip/hip_fp16.h>

#define DD 300
#define SS 512
#define NW 16          // waves per block in main kernel
#define NF4 75         // float4 per 300-float row

// Workspace layout (float index):
//   0: c_k   1: c_q
//   16..316   : u  = wk @ Wk
//   320..620  : uq = wq @ Wq
//   640..940  : bc = Wp @ bk + bp
//   1024..91024   : Wc = Wp @ Wk (300x300)
//   91648..141648 : eu[v] = dot(emb[v], u)  (50000)
//   143360..      : emb16 (50000 rows x 300 half = 600B/row, ushort4[75]/row)
#define WC_OFF  1024
#define EU_OFF  91648
#define E16_OFF 143360
#define VV 50000

#define FMA4(acc, s, v) { acc.x += (s)*(v).x; acc.y += (s)*(v).y; \
                          acc.z += (s)*(v).z; acc.w += (s)*(v).w; }

// ---------------------------------------------------------------------------
// K1: all weight-side precompute. 102 blocks x 1024 threads.
//   blocks 0..99 : Wc rows 3b..3b+2 (row-major accumulation, coalesced)
//   block 100    : u = wk@Wk, c_k
//   block 101    : uq = wq@Wq, c_q, bc = Wp@bk + bp
// ---------------------------------------------------------------------------
__global__ __launch_bounds__(1024) void precompute(
    const float* __restrict__ Wk, const float* __restrict__ bk,
    const float* __restrict__ Wq, const float* __restrict__ bq,
    const float* __restrict__ w_mlp,
    const float* __restrict__ Wp, const float* __restrict__ bp,
    float* __restrict__ ws)
{
    const int blk  = blockIdx.x;
    const int tid  = threadIdx.x;
    const int wv   = tid >> 6;
    const int lane = tid & 63;
    __shared__ __align__(16) float buf[16 * 304 * 3 + 3 * 304];  // 62 KB
    __shared__ float red[16];

    if (blk < 100) {
        const int i0 = blk * 3;
        float* sWp = buf + 16 * 304 * 3;          // [3][304]
        for (int r = tid; r < 3 * DD; r += 1024)
            sWp[(r / DD) * 304 + (r % DD)] = Wp[i0 * DD + r];
        __syncthreads();

        float4 a00{0,0,0,0}, a01{0,0,0,0}, a10{0,0,0,0},
               a11{0,0,0,0}, a20{0,0,0,0}, a21{0,0,0,0};
        for (int e = wv; e < DD; e += NW) {
            const float4* kr = (const float4*)(Wk + e * DD);
            const float4 k0 = kr[lane];
            const float p0 = sWp[e], p1 = sWp[304 + e], p2 = sWp[608 + e];
            FMA4(a00, p0, k0); FMA4(a10, p1, k0); FMA4(a20, p2, k0);
            if (lane < 11) {
                const float4 k1 = kr[64 + lane];
                FMA4(a01, p0, k1); FMA4(a11, p1, k1); FMA4(a21, p2, k1);
            }
        }
        // partials: buf as [16][3][304]
        float4* p0r = (float4*)(buf + (wv * 3 + 0) * 304);
        float4* p1r = (float4*)(buf + (wv * 3 + 1) * 304);
        float4* p2r = (float4*)(buf + (wv * 3 + 2) * 304);
        p0r[lane] = a00; p1r[lane] = a10; p2r[lane] = a20;
        if (lane < 11) { p0r[64+lane] = a01; p1r[64+lane] = a11; p2r[64+lane] = a21; }
        __syncthreads();
        if (tid < DD) {
            #pragma unroll
            for (int r = 0; r < 3; ++r) {
                float s = 0.f;
                for (int w = 0; w < NW; ++w) s += buf[(w * 3 + r) * 304 + tid];
                ws[WC_OFF + (i0 + r) * DD + tid] = s;
            }
        }
        return;
    }

    // blocks 100/101: vector-matrix accumulations
    const float* M  = (blk == 100) ? Wk : Wq;
    const float* vw = (blk == 100) ? w_mlp : (w_mlp + DD);
    float* s_w = buf + 16 * 304;                  // 300
    float* s_b = buf + 16 * 304 + 304;            // 300 (bk, block 101)
    if (tid < DD) {
        s_w[tid] = vw[tid];
        if (blk == 101) s_b[tid] = bk[tid];
    }
    __syncthreads();

    float4 a0{0,0,0,0}, a1{0,0,0,0};
    for (int e = wv; e < DD; e += NW) {
        const float4* kr = (const float4*)(M + e * DD);
        const float s = s_w[e];
        const float4 k0 = kr[lane];
        FMA4(a0, s, k0);
        if (lane < 11) { const float4 k1 = kr[64 + lane]; FMA4(a1, s, k1); }
    }
    float4* pr = (float4*)(buf + wv * 304);
    pr[lane] = a0;
    if (lane < 11) pr[64 + lane] = a1;

    // scalar c = dot(bias, vw)
    float pk = 0.f;
    if (tid < DD) pk = ((blk == 100) ? bk[tid] : bq[tid]) * s_w[tid];
    #pragma unroll
    for (int off = 32; off; off >>= 1) pk += __shfl_xor(pk, off);
    if (lane == 0) red[wv] = pk;
    __syncthreads();

    const int voff = (blk == 100) ? 16 : 320;
    if (tid < DD) {
        float s = 0.f;
        #pragma unroll
        for (int w = 0; w < NW; ++w) s += buf[w * 304 + tid];
        ws[voff + tid] = s;
    }
    if (tid == 0) {
        float s = 0.f;
        for (int w = 0; w < NW; ++w) s += red[w];
        ws[(blk == 100) ? 0 : 1] = s;
    }
    if (blk == 101 && tid < DD) {
        // bc[tid] = dot(Wp row tid, bk) + bp[tid]
        const float4* wr = (const float4*)(Wp + tid * DD);
        const float4* b4 = (const float4*)s_b;
        float a = 0.f;
        for (int j = 0; j < NF4; ++j) {
            const float4 w4 = wr[j];
            const float4 bb = b4[j];            // LDS broadcast
            a += w4.x * bb.x + w4.y * bb.y + w4.z * bb.z + w4.w * bb.w;
        }
        ws[640 + tid] = a + bp[tid];
    }
}

// ---------------------------------------------------------------------------
// K2: one streaming pass over emb: eu[v] = dot(emb[v], u), and fp16 copy.
// Wave per row, grid-stride. 512 x 1024.
// ---------------------------------------------------------------------------
__global__ __launch_bounds__(1024) void build_tables(
    const float* __restrict__ emb, float* __restrict__ ws, const int do16)
{
    const int tid  = threadIdx.x;
    const int wv   = tid >> 6;
    const int lane = tid & 63;
    __shared__ __align__(16) float u_s[DD];
    if (tid < DD) u_s[tid] = ws[16 + tid];
    __syncthreads();

    const float4* u4 = (const float4*)u_s;
    const float4  q0 = u4[lane];
    const float4  q1 = (lane < 11) ? u4[64 + lane] : float4{0, 0, 0, 0};
    ushort4* e16 = (ushort4*)(ws + E16_OFF);

    const int gw     = blockIdx.x * (1024 / 64) + wv;
    const int stride = gridDim.x * (1024 / 64);
    for (int v = gw; v < VV; v += stride) {
        const float4* er = (const float4*)(emb + (size_t)v * DD);
        const float4 e0 = er[lane];
        float4 e1{0, 0, 0, 0};
        float a = e0.x * q0.x + e0.y * q0.y + e0.z * q0.z + e0.w * q0.w;
        if (lane < 11) {
            e1 = er[64 + lane];
            a += e1.x * q1.x + e1.y * q1.y + e1.z * q1.z + e1.w * q1.w;
        }
        #pragma unroll
        for (int off = 32; off; off >>= 1) a += __shfl_xor(a, off);
        if (lane == 0) ws[EU_OFF + v] = a;
        if (do16) {
            ushort4 h0;
            h0.x = __half_as_ushort(__float2half(e0.x));
            h0.y = __half_as_ushort(__float2half(e0.y));
            h0.z = __half_as_ushort(__float2half(e0.z));
            h0.w = __half_as_ushort(__float2half(e0.w));
            e16[(size_t)v * NF4 + lane] = h0;
            if (lane < 11) {
                ushort4 h1;
                h1.x = __half_as_ushort(__float2half(e1.x));
                h1.y = __half_as_ushort(__float2half(e1.y));
                h1.z = __half_as_ushort(__float2half(e1.z));
                h1.w = __half_as_ushort(__float2half(e1.w));
                e16[(size_t)v * NF4 + 64 + lane] = h1;
            }
        }
    }
}

// ---------------------------------------------------------------------------
// K3: main kernel. One block per batch row, 1024 threads = 16 waves.
// ---------------------------------------------------------------------------
__global__ __launch_bounds__(1024, 8) void memnet_main(
    const int* __restrict__ text, const int* __restrict__ asp,
    const float* __restrict__ emb,
    const float* __restrict__ Wx, const float* __restrict__ bx,
    const float* __restrict__ Wd, const float* __restrict__ bd,
    const float* __restrict__ ws,
    float* __restrict__ out, const int use16)
{
    const int b    = blockIdx.x;
    const int tid  = threadIdx.x;
    const int wv   = tid >> 6;
    const int lane = tid & 63;

    __shared__ __align__(16) float ks[SS];
    __shared__ __align__(16) float cw[SS];
    __shared__ __align__(16) float wgt[SS];
    __shared__ __align__(16) int   ti[SS];
    __shared__ __align__(16) float xv[DD];
    __shared__ __align__(16) float xn[DD];
    __shared__ __align__(16) float mv[DD];
    __shared__ __align__(16) float uq_s[DD];
    __shared__ __align__(16) float mpart[NW][DD];
    __shared__ float red[NW];
    __shared__ float red2[NW];

    // ---- tokens + length ----
    int t = 0;
    if (tid < SS) { t = text[(size_t)b * SS + tid]; ti[tid] = t; }
    const unsigned long long bal = __ballot(tid < SS && t != 0);
    if (lane == 0) red[wv] = (float)__popcll(bal);
    __syncthreads();

    int len = 0;
    #pragma unroll
    for (int w = 0; w < NW; ++w) len += (int)red[w];
    const float lenf = (float)len;
    const int   s0   = SS - len;

    const float c_k = ws[0];
    const float c_q = ws[1];

    if (tid < SS) {
        const int j = tid - s0;
        const float wg = (j >= 0) ? (1.0f - (float)j / lenf) : 1.0f;
        wgt[tid] = wg;
        ks[tid]  = wg * ws[EU_OFF + t] + c_k;   // eu[0]==0 -> pad ks = c_k
    }

    if (tid < DD) {
        uq_s[tid] = ws[320 + tid];
        float na = 0.f, a = 0.f;
        #pragma unroll
        for (int k = 0; k < 8; ++k) {
            const int idx = asp[b * 8 + k];
            na += (idx != 0) ? 1.0f : 0.0f;
            a += emb[(size_t)idx * DD + tid];
        }
        xv[tid] = a / na;
    }
    __syncthreads();

    const ushort4* e16 = (const ushort4*)(ws + E16_OFF);

    // ---- hop loop ----
    for (int hop = 0; hop < 3; ++hop) {
        // xn = Wx @ xv + bx (+ fold qs partial)
        {
            const float4* x4 = (const float4*)xv;
            const float4  v0 = x4[lane];
            const float4  v1 = (lane < 11) ? x4[64 + lane] : float4{0, 0, 0, 0};
            float qpart = 0.f;
            for (int i = wv; i < DD; i += NW) {
                const float4* wr = (const float4*)(Wx + i * DD);
                const float4 w0 = wr[lane];
                float a = w0.x * v0.x + w0.y * v0.y + w0.z * v0.z + w0.w * v0.w;
                if (lane < 11) {
                    const float4 w1 = wr[64 + lane];
                    a += w1.x * v1.x + w1.y * v1.y + w1.z * v1.z + w1.w * v1.w;
                }
                #pragma unroll
                for (int off = 32; off; off >>= 1) a += __shfl_xor(a, off);
                if (lane == 0) {
                    const float xni = a + bx[i];
                    xn[i] = xni;
                    qpart += uq_s[i] * xni;
                }
            }
            if (lane == 0) red[wv] = qpart;
        }
        __syncthreads();

        float qs = c_q;
        #pragma unroll
        for (int w = 0; w < NW; ++w) qs += red[w];

        float p = 0.f;
        if (tid < SS) {
            p = expf(tanhf(ks[tid] + qs));
            cw[tid] = p * wgt[tid];
        }
        float sp = p;
        #pragma unroll
        for (int off = 32; off; off >>= 1) sp += __shfl_xor(sp, off);
        if (lane == 0) red2[wv] = sp;
        __syncthreads();

        float sumP = 0.f;
        #pragma unroll
        for (int w = 0; w < NW; ++w) sumP += red2[w];

        // m = sum_{s>=s0} cw[s]*emb[t[s]]
        {
            float4 acc{0, 0, 0, 0}, accb{0, 0, 0, 0};
            const int start = s0 + ((wv - s0) & (NW - 1));
            if (use16) {
                #pragma unroll 4
                for (int s = start; s < SS; s += NW) {
                    const int row = ti[s];
                    const float c = cw[s];
                    const ushort4* r16 = e16 + (size_t)row * NF4;
                    const ushort4 h0 = r16[lane];
                    const float2 f0 = __half22float2(*(const __half2*)&h0.x);
                    const float2 f1 = __half22float2(*(const __half2*)&h0.z);
                    acc.x += c * f0.x; acc.y += c * f0.y;
                    acc.z += c * f1.x; acc.w += c * f1.y;
                    if (lane < 11) {
                        const ushort4 h1 = r16[64 + lane];
                        const float2 g0 = __half22float2(*(const __half2*)&h1.x);
                        const float2 g1 = __half22float2(*(const __half2*)&h1.z);
                        accb.x += c * g0.x; accb.y += c * g0.y;
                        accb.z += c * g1.x; accb.w += c * g1.y;
                    }
                }
            } else {
                #pragma unroll 4
                for (int s = start; s < SS; s += NW) {
                    const int row = ti[s];
                    const float c = cw[s];
                    const float4* er = (const float4*)(emb + (size_t)row * DD);
                    const float4 e0 = er[lane];
                    acc.x += c * e0.x; acc.y += c * e0.y;
                    acc.z += c * e0.z; acc.w += c * e0.w;
                    if (lane < 11) {
                        const float4 e1 = er[64 + lane];
                        accb.x += c * e1.x; accb.y += c * e1.y;
                        accb.z += c * e1.z; accb.w += c * e1.w;
                    }
                }
            }
            ((float4*)&mpart[wv][0])[lane] = acc;
            if (lane < 11) ((float4*)&mpart[wv][0])[64 + lane] = accb;
        }
        __syncthreads();

        if (tid < DD) {
            float mm = 0.f;
            #pragma unroll
            for (int w = 0; w < NW; ++w) mm += mpart[w][tid];
            mv[tid] = mm / sumP;
        }
        __syncthreads();

        // xv = Wc @ mv + bc + xn
        {
            const float* Wc = ws + WC_OFF;
            const float* bc = ws + 640;
            const float4* m4 = (const float4*)mv;
            const float4  v0 = m4[lane];
            const float4  v1 = (lane < 11) ? m4[64 + lane] : float4{0, 0, 0, 0};
            for (int i = wv; i < DD; i += NW) {
                const float4* wr = (const float4*)(Wc + i * DD);
                const float4 w0 = wr[lane];
                float a = w0.x * v0.x + w0.y * v0.y + w0.z * v0.z + w0.w * v0.w;
                if (lane < 11) {
                    const float4 w1 = wr[64 + lane];
                    a += w1.x * v1.x + w1.y * v1.y + w1.z * v1.z + w1.w * v1.w;
                }
                #pragma unroll
                for (int off = 32; off; off >>= 1) a += __shfl_xor(a, off);
                if (lane == 0) xv[i] = a + bc[i] + xn[i];
            }
        }
        __syncthreads();
    }

    // ---- out ----
    if (wv < 3) {
        const float4* wr = (const float4*)(Wd + wv * DD);
        const float4* x4 = (const float4*)xv;
        const float4 w0 = wr[lane];
        const float4 v0 = x4[lane];
        float a = w0.x * v0.x + w0.y * v0.y + w0.z * v0.z + w0.w * v0.w;
        if (lane < 11) {
            const float4 w1 = wr[64 + lane];
            const float4 v1 = x4[64 + lane];
            a += w1.x * v1.x + w1.y * v1.y + w1.z * v1.z + w1.w * v1.w;
        }
        #pragma unroll
        for (int off = 32; off; off >>= 1) a += __shfl_xor(a, off);
        if (lane == 0) out[b * 3 + wv] = a + bd[wv];
    }
}

extern "C" void kernel_launch(void* const* d_in, const int* in_sizes, int n_in,
                              void* d_out, int out_size, void* d_ws, size_t ws_size,
                              hipStream_t stream)
{
    const int*   text = (const int*)d_in[0];
    const int*   asp  = (const int*)d_in[1];
    const float* emb  = (const float*)d_in[2];
    const float* Wx   = (const float*)d_in[3];
    const float* bx   = (const float*)d_in[4];
    const float* Wk   = (const float*)d_in[5];
    const float* bk   = (const float*)d_in[6];
    const float* Wq   = (const float*)d_in[7];
    const float* bq   = (const float*)d_in[8];
    const float* wm   = (const float*)d_in[9];
    const float* Wp   = (const float*)d_in[10];
    const float* bp   = (const float*)d_in[11];
    const float* Wd   = (const float*)d_in[12];
    const float* bd   = (const float*)d_in[13];
    float* out = (float*)d_out;
    float* ws  = (float*)d_ws;

    const size_t need = (size_t)E16_OFF * 4 + (size_t)VV * DD * 2;
    const int use16 = (ws_size >= need) ? 1 : 0;

    precompute<<<102, 1024, 0, stream>>>(Wk, bk, Wq, bq, wm, Wp, bp, ws);
    build_tables<<<512, 1024, 0, stream>>>(emb, ws, use16);
    memnet_main<<<512, 1024, 0, stream>>>(text, asp, emb, Wx, bx, Wd, bd, ws, out, use16);
}